// Round 6
// baseline (705.120 us; speedup 1.0000x reference)
//
#include <hip/hip_runtime.h>
#include <stdint.h>

// ---------------------------------------------------------------------------
// Ternary 3x3 conv block via i8 MFMA implicit GEMM, phase-overlapped.
//
// Activations: NHWC i8 ternary {-1,0,+1}, padded [64][58][58][256], halo = 0.
// Weights pre-packed in MFMA B-fragment order:
//   Bpk[nfrag(16)][unit(36)][lane(64)][16B], unit = tap*4 + cich (k-chunk).
// mconv block: 2 h2-tiles per block (M=112 x N=256 x K=2304 each), 8 waves
//   N-split 32 (acc[7][2] = 56 AGPRs), 4 rows in LDS slots (slot = row&3).
//   Round-5 counters closed the model: per round staging 2 + K 10.5 (LDS-
//   bound) + epilogue 9 (HBM at per-CU share) run FULLY SERIAL = 21.5us x 7
//   = 151 ~= 156 measured. Cause: __syncthreads emits s_waitcnt vmcnt(0)
//   before s_barrier -> epilogue stores drain before next staging.
// Round-6 change (T3/T4-minimal): raw s_barrier + lgkmcnt(0)-only barriers
//   (stores stay in flight), 2-tile blocks (tile1 re-stages only 2 rows into
//   slots 0,1; rows 2,3 reused), epilogues confined to LDS slots 0,1
//   (stage-2: four 64-co quarters of [cop][FST=116dw]). Tile-0 store drain
//   hides under tile-1 staging + K-loop.
//   C/D: col=lane&15, row=(lane>>4)*4+reg.
// ---------------------------------------------------------------------------

#define NB 64
#define C  256
#define H  56
#define W  56
#define HP 58
#define PPIX 272                 // padded bytes per pixel in LDS (17*16)
#define SLOT (HP * PPIX)         // bytes per LDS row slot
#define OST 272                  // stage-1 transpose row stride (256+16)
#define FST 116                  // stage-2 transpose stride in dwords (112+4)

typedef int v4i __attribute__((ext_vector_type(4)));

// Barrier WITHOUT vmcnt drain: LDS-visibility only. Global stores/loads keep
// flowing across it (the whole point). Rule-18 fencing around inline asm.
__device__ __forceinline__ void wg_barrier() {
    __builtin_amdgcn_sched_barrier(0);
    asm volatile("s_waitcnt lgkmcnt(0)" ::: "memory");
    __builtin_amdgcn_sched_barrier(0);
    __builtin_amdgcn_s_barrier();
    __builtin_amdgcn_sched_barrier(0);
}

// ---------------- pack input: NCHW fp32 -> padded NHWC ternary i8 ----------
__global__ __launch_bounds__(256)
void pack_x_kernel(const float* __restrict__ x, int8_t* __restrict__ Aq) {
    const int h = blockIdx.x, n = blockIdx.y;
    const int w  = threadIdx.x & 63;   // 0..55 valid
    const int cq = threadIdx.x >> 6;   // 64-channel group

    __shared__ int8_t st[56 * OST];    // [w][c] ternary bytes, padded stride

    const float* xp = x + (((size_t)n * C + cq * 64) * H + h) * W + w;
#pragma unroll
    for (int i = 0; i < 16; ++i) {     // 4 channels per iter -> one u32 store
        uint32_t u = 0;
#pragma unroll
        for (int b = 0; b < 4; ++b) {
            float v = (w < 56) ? xp[(size_t)(i * 4 + b) * (H * W)] : 0.0f;
            uint32_t t = (v < 0.0f) ? 0xFFu : ((v != 0.0f) ? 1u : 0u);
            u |= t << (8 * b);
        }
        if (w < 56)
            *(uint32_t*)(st + w * OST + cq * 64 + i * 4) = u;
    }
    __syncthreads();
    // coalesced out: 56 pixels x 256 B contiguous at (h+1, 1)
    int8_t* dst = Aq + (((size_t)n * HP + h + 1) * HP + 1) * C;
    for (int idx = threadIdx.x; idx < 56 * 16; idx += 256) {
        int pix = idx >> 4, c16 = idx & 15;
        *(v4i*)(dst + (size_t)pix * C + c16 * 16) =
            *(const v4i*)(st + pix * OST + c16 * 16);
    }
}

// ---------------- pack weights into B-fragment order -----------------------
__global__ __launch_bounds__(64)
void pack_w_kernel(const float* __restrict__ wa, const float* __restrict__ wb,
                   int8_t* __restrict__ B1, int8_t* __restrict__ B2) {
    const int kstep = blockIdx.x;   // 0..35 (= tap*4 + cich)
    const int nfrag = blockIdx.y;   // 0..15
    const float* wsrc = blockIdx.z ? wb : wa;
    int8_t* dst       = blockIdx.z ? B2 : B1;
    const int lane = threadIdx.x, quad = lane >> 4, l16 = lane & 15;
    const int co = nfrag * 16 + l16;
    uint32_t pk[4];
#pragma unroll
    for (int d = 0; d < 4; ++d) {
        uint32_t u = 0;
#pragma unroll
        for (int bb = 0; bb < 4; ++bb) {
            int k = kstep * 64 + quad * 16 + d * 4 + bb;
            int tap = k >> 8, ci = k & 255;
            float v = wsrc[((size_t)co * C + ci) * 9 + tap];
            uint32_t t = (v < 0.0f) ? 0xFFu : ((v != 0.0f) ? 1u : 0u);
            u |= t << (8 * bb);
        }
        pk[d] = u;
    }
    uint4 st; st.x = pk[0]; st.y = pk[1]; st.z = pk[2]; st.w = pk[3];
    *(uint4*)(dst + ((size_t)(nfrag * 36 + kstep) * 64 + lane) * 16) = st;
}

// ---------------- zero halos of both padded activation buffers -------------
__global__ __launch_bounds__(256)
void halo_zero_kernel(int8_t* __restrict__ Aq, int8_t* __restrict__ Bq) {
    const int n = blockIdx.x;
    int8_t* buf = blockIdx.y ? Bq : Aq;
    const v4i z = (v4i){0, 0, 0, 0};
    for (int idx = threadIdx.x; idx < 228 * 16; idx += 256) {
        int px = idx >> 4, c16 = idx & 15;
        int row, col;
        if (px < 58)       { row = 0;  col = px; }
        else if (px < 116) { row = 57; col = px - 58; }
        else { int i = px - 116; row = 1 + (i >> 1); col = (i & 1) * 57; }
        *(v4i*)(buf + (((size_t)n * HP + row) * HP + col) * C + c16 * 16) = z;
    }
}

// ---------------- BN constants (match prior absmax-0 double path) ----------
__global__ __launch_bounds__(256)
void bn_prep_kernel(const float* g1, const float* b1, const float* m1, const float* v1,
                    const float* g2, const float* b2, const float* m2, const float* v2,
                    float* __restrict__ sc, float* __restrict__ sh) {
    const int co = threadIdx.x;
    const float* g = blockIdx.x ? g2 : g1;
    const float* b = blockIdx.x ? b2 : b1;
    const float* m = blockIdx.x ? m2 : m1;
    const float* v = blockIdx.x ? v2 : v1;
    double scd = (double)g[co] / sqrt((double)v[co] + 1e-5);
    sc[blockIdx.x * C + co] = (float)scd;
    sh[blockIdx.x * C + co] = (float)((double)b[co] - (double)m[co] * scd);
}

// ---------------- the conv kernels -----------------------------------------
// STAGE 1: GEMM -> BN -> ternarize -> LDS transpose (slots 0,1) -> NHWC i8.
// STAGE 2: GEMM -> BN -> LDS transpose quarters (slots 0,1) -> +residual ->
//          clip -> fp32 NCHW (w-contiguous float4 runs).
// 512 threads = 8 waves; wave wv owns nfrags {wv*2, wv*2+1} (N-cols wv*32..+31).
// Block bx handles h2-tiles {2bx, 2bx+1}; input rows 4bx..4bx+5, slot = row&3.
template <int STAGE>
__global__ __launch_bounds__(512, 4)
void mconv_kernel(const int8_t* __restrict__ Aq, const int8_t* __restrict__ Bpk,
                  const float* __restrict__ scp, const float* __restrict__ shp,
                  const float* __restrict__ resid,
                  int8_t* __restrict__ Bout, float* __restrict__ out) {
    const int bx = blockIdx.x;   // 0..13
    const int n  = blockIdx.y;
    const int tid = threadIdx.x;
    const int wv = tid >> 6, lane = tid & 63, quad = lane >> 4, l16 = lane & 15;

    __shared__ int8_t lds[4 * SLOT];   // 63104 B -> 2 blocks/CU

    // per-lane A-base pieces (tile-independent): m = f*16 + l16 -> (hl, w)
    int wb[7], hlf[7];
#pragma unroll
    for (int f = 0; f < 7; ++f) {
        int mm = f * 16 + l16;
        int hl = (mm >= 56) ? 1 : 0;
        wb[f]  = (mm - 56 * hl) * PPIX + quad * 16;
        hlf[f] = hl;
    }

    // BN constants for this thread's two channels (used every tile)
    const int co0 = wv * 32 + l16, co1 = co0 + 16;
    const float sc0 = scp[co0], sh0 = shp[co0];
    const float sc1 = scp[co1], sh1 = shp[co1];

    const int8_t* bq0_base = Bpk + (size_t)((wv * 2 + 0) * 36) * 1024 + lane * 16;
    const int8_t* bq1_base = Bpk + (size_t)((wv * 2 + 1) * 36) * 1024 + lane * 16;

#pragma unroll 1
    for (int tt = 0; tt < 2; ++tt) {
        const int OH0 = 4 * bx + 2 * tt;   // first output row of this tile

        // ---- staging: tile0 -> 4 rows into slots 0..3; tile1 -> rows
        //      4bx+4,4bx+5 into slots 0,1 (slots 2,3 reused from tile0).
        {
            const int base_row = 4 * bx + (tt ? 4 : 0);
            const int npix = (tt ? 2 : 4) * HP * 16;
            const int8_t* gA = Aq + ((size_t)n * HP + base_row) * HP * C;
            for (int idx = tid; idx < npix; idx += 512) {
                int pix = idx >> 4, c16 = idx & 15;    // pix = slot*HP + col
                *(v4i*)(lds + pix * PPIX + c16 * 16) =
                    *(const v4i*)(gA + (size_t)pix * C + c16 * 16);
            }
        }
        wg_barrier();   // A-tile visible; prior tile's stores still in flight

        // ---- K-loop ----
        const int8_t* bq0 = bq0_base;
        const int8_t* bq1 = bq1_base;
        v4i bcur0 = *(const v4i*)bq0;
        v4i bcur1 = *(const v4i*)bq1;

        v4i acc[7][2];
#pragma unroll
        for (int f = 0; f < 7; ++f)
#pragma unroll
            for (int nf = 0; nf < 2; ++nf) acc[f][nf] = (v4i){0, 0, 0, 0};

#pragma unroll 1
        for (int t9 = 0; t9 < 9; ++t9) {
            const int r = (t9 >= 6) ? 2 : ((t9 >= 3) ? 1 : 0);
            const int c = t9 - 3 * r;
            // slot of input row (OH0 + r + hl) = (2*tt + r + hl) & 3
            const int s0 = (((tt << 1) + r) & 3) * SLOT + c * PPIX;
            const int s1 = (((tt << 1) + r + 1) & 3) * SLOT + c * PPIX;
            const int ds = s1 - s0;
#pragma unroll
            for (int ci = 0; ci < 4; ++ci) {
                // prefetch next unit's B (flat-contiguous; final iteration
                // reads 1KB past this nfrag's tail -> still inside d_ws)
                v4i bn0 = *(const v4i*)(bq0 + (ci + 1) * 1024);
                v4i bn1 = *(const v4i*)(bq1 + (ci + 1) * 1024);
                v4i afr[7];
#pragma unroll
                for (int f = 0; f < 7; ++f)
                    afr[f] = *(const v4i*)(lds + s0 + hlf[f] * ds + wb[f] + ci * 64);
                __builtin_amdgcn_s_setprio(1);
#pragma unroll
                for (int f = 0; f < 7; ++f) {
                    acc[f][0] = __builtin_amdgcn_mfma_i32_16x16x64_i8(
                        afr[f], bcur0, acc[f][0], 0, 0, 0);
                    acc[f][1] = __builtin_amdgcn_mfma_i32_16x16x64_i8(
                        afr[f], bcur1, acc[f][1], 0, 0, 0);
                }
                __builtin_amdgcn_s_setprio(0);
                bcur0 = bn0;
                bcur1 = bn1;
            }
            bq0 += 4096;
            bq1 += 4096;
        }

        // ---- epilogue (confined to LDS slots 0,1 = bytes < 2*SLOT) ----
        if (STAGE == 1) {
            wg_barrier();   // K-loop LDS reads done; reuse as [mm][co] bytes
#pragma unroll
            for (int nf = 0; nf < 2; ++nf) {
                const int co = wv * 32 + nf * 16 + l16;
                const float scale = nf ? sc1 : sc0;
                const float shift = nf ? sh1 : sh0;
#pragma unroll
                for (int f = 0; f < 7; ++f) {
#pragma unroll
                    for (int reg = 0; reg < 4; ++reg) {
                        int mm = f * 16 + quad * 4 + reg;
                        float v = __fadd_rn(__fmul_rn((float)acc[f][nf][reg], scale), shift);
                        int8_t t8 = (v < 0.0f) ? (int8_t)-1
                                  : ((v != 0.0f) ? (int8_t)1 : (int8_t)0);
                        lds[mm * OST + co] = t8;   // max 30,463 < 2*SLOT
                    }
                }
            }
            wg_barrier();
            // coalesced out: 112 pixels x 256 B
#pragma unroll
            for (int k = 0; k < 4; ++k) {
                int idx = tid + k * 512;
                if (idx < 112 * 16) {
                    int mm = idx >> 4, c16 = idx & 15;
                    int hl = (mm >= 56) ? 1 : 0;
                    int ww = mm - 56 * hl;
                    int oh = OH0 + hl;
                    *(v4i*)(Bout + (((size_t)n * HP + oh + 1) * HP + ww + 1) * C + c16 * 16)
                        = *(const v4i*)(lds + mm * OST + c16 * 16);
                }
            }
            wg_barrier();   // LDS reads done before next tile's staging
        } else {
            float* fld = (float*)lds;   // [cop(64)][FST dw] = 29,696 B < 2*SLOT
#pragma unroll 1
            for (int qtr = 0; qtr < 4; ++qtr) {
                wg_barrier();           // prior users of region done
                if ((wv >> 1) == qtr) { // waves 2q,2q+1 own co = 64q..64q+63
#pragma unroll
                    for (int nf = 0; nf < 2; ++nf) {
                        const int cop = (wv * 32 + nf * 16 + l16) & 63;
                        const float scale = nf ? sc1 : sc0;
                        const float shift = nf ? sh1 : sh0;
#pragma unroll
                        for (int f = 0; f < 7; ++f) {
                            float4 vv;
                            vv.x = __fadd_rn(__fmul_rn((float)acc[f][nf][0], scale), shift);
                            vv.y = __fadd_rn(__fmul_rn((float)acc[f][nf][1], scale), shift);
                            vv.z = __fadd_rn(__fmul_rn((float)acc[f][nf][2], scale), shift);
                            vv.w = __fadd_rn(__fmul_rn((float)acc[f][nf][3], scale), shift);
                            *(float4*)(fld + cop * FST + f * 16 + quad * 4) = vv;
                        }
                    }
                }
                wg_barrier();
                // 64 co x 28 float4-chunks (2 rows x 14) = 1792 = 512*3.5
#pragma unroll
                for (int k = 0; k < 4; ++k) {
                    int idx = tid + k * 512;
                    if (idx < 64 * 28) {
                        int cop = idx / 28, j = idx - cop * 28;
                        int row = (j >= 14) ? 1 : 0;
                        int w4  = (j - row * 14) * 4;
                        int co  = qtr * 64 + cop;
                        float4 v = *(const float4*)(fld + cop * FST + row * 56 + w4);
                        size_t gidx = (((size_t)n * C + co) * H + OH0 + row) * W + w4;
                        float4 rv = *(const float4*)(resid + gidx);
                        float4 ov;
                        ov.x = fminf(1.0f, fmaxf(-1.0f, v.x + rv.x));
                        ov.y = fminf(1.0f, fmaxf(-1.0f, v.y + rv.y));
                        ov.z = fminf(1.0f, fmaxf(-1.0f, v.z + rv.z));
                        ov.w = fminf(1.0f, fmaxf(-1.0f, v.w + rv.w));
                        *(float4*)(out + gidx) = ov;
                    }
                }
            }
            wg_barrier();   // fld reads done before next tile's staging
        }
    }
}

extern "C" void kernel_launch(void* const* d_in, const int* in_sizes, int n_in,
                              void* d_out, int out_size, void* d_ws, size_t ws_size,
                              hipStream_t stream) {
    const float* x  = (const float*)d_in[0];
    const float* w1 = (const float*)d_in[1];
    const float* g1 = (const float*)d_in[2];
    const float* b1 = (const float*)d_in[3];
    const float* m1 = (const float*)d_in[4];
    const float* v1 = (const float*)d_in[5];
    const float* w2 = (const float*)d_in[6];
    const float* g2 = (const float*)d_in[7];
    const float* b2 = (const float*)d_in[8];
    const float* m2 = (const float*)d_in[9];
    const float* v2 = (const float*)d_in[10];
    float* out = (float*)d_out;

    uint8_t* ws = (uint8_t*)d_ws;
    const size_t ASZ = (size_t)NB * HP * HP * C;       // 55,083,008 B per act buffer
    const size_t WPK = (size_t)16 * 36 * 64 * 16;      // 589,824 B per packed weight
    int8_t* Aq   = (int8_t*)(ws);
    int8_t* Bq   = (int8_t*)(ws + ASZ);
    int8_t* Bpk1 = (int8_t*)(ws + 2 * ASZ);
    int8_t* Bpk2 = (int8_t*)(ws + 2 * ASZ + WPK);
    float*  scb  = (float*)(ws + 2 * ASZ + 2 * WPK);           // [2][256]
    float*  shb  = (float*)(ws + 2 * ASZ + 2 * WPK + 2048);    // [2][256]

    halo_zero_kernel<<<dim3(NB, 2), 256, 0, stream>>>(Aq, Bq);
    bn_prep_kernel<<<dim3(2), 256, 0, stream>>>(g1, b1, m1, v1, g2, b2, m2, v2,
                                                scb, shb);
    pack_w_kernel<<<dim3(36, 16, 2), 64, 0, stream>>>(w1, w2, Bpk1, Bpk2);
    pack_x_kernel<<<dim3(H, NB), 256, 0, stream>>>(x, Aq);
    mconv_kernel<1><<<dim3(14, NB), 512, 0, stream>>>(Aq, Bpk1, scb, shb,
                                                      nullptr, Bq, nullptr);
    mconv_kernel<2><<<dim3(14, NB), 512, 0, stream>>>(Bq, Bpk2, scb + C, shb + C,
                                                      x, nullptr, out);
}

// Round 7
// 638.609 us; speedup vs baseline: 1.1041x; 1.1041x over previous
//
#include <hip/hip_runtime.h>
#include <stdint.h>

// ---------------------------------------------------------------------------
// Ternary 3x3 conv block via i8 MFMA implicit GEMM.
//
// Activations: NHWC i8 ternary {-1,0,+1}, padded [64][58][58][256], halo = 0.
// Weights pre-packed in MFMA B-fragment order:
//   Bpk[nfrag(16)][unit(36)][lane(64)][16B], unit = tap*4 + cich (k-chunk).
// mconv block (round-7): M=112 (2 out rows) x N=256 x K=2304, 8 waves in a
//   2Mx4N grid: wave (wrow=wv>>2, wcol=wv&3) owns m-frags {wrow*4..} (4 for
//   wrow0, 3 for wrow1 -- uneven, no pad MFMA) x nfrags {wcol*4..wcol*4+3}.
//   acc[4][4] = 64 AGPRs, NO B-dbuf (B is L2-resident; 4 waves/SIMD hide
//   latency) -> ~124 unified regs, 2 blocks/CU (LDS 63.1 KB).
//   WHY (round-5 counters): N-split-8 waves each re-read the FULL A tile:
//   56 ds_read_b128/unit/block -> LDS pipe time == MFMA pipe time (41k cyc
//   per CU pair-round each) -> K-phase bound by both. 2Mx4N halves A-reads
//   (28/unit). Round-6's 2-tile overlap attempt spilled acc (+103 MB scratch
//   writes) -> reverted; __syncthreads barriers restored.
//   C/D: col=lane&15, row=(lane>>4)*4+reg.
// ---------------------------------------------------------------------------

#define NB 64
#define C  256
#define H  56
#define W  56
#define HP 58
#define PPIX 272                 // padded bytes per pixel in LDS (17*16)
#define SLOT (HP * PPIX)         // bytes per LDS row slot
#define OST 272                  // stage-1 transpose row stride (256+16)
#define FST 116                  // stage-2 transpose stride in dwords (112+4)

typedef int v4i __attribute__((ext_vector_type(4)));

// ---------------- pack input: NCHW fp32 -> padded NHWC ternary i8 ----------
__global__ __launch_bounds__(256)
void pack_x_kernel(const float* __restrict__ x, int8_t* __restrict__ Aq) {
    const int h = blockIdx.x, n = blockIdx.y;
    const int w  = threadIdx.x & 63;   // 0..55 valid
    const int cq = threadIdx.x >> 6;   // 64-channel group

    __shared__ int8_t st[56 * OST];    // [w][c] ternary bytes, padded stride

    const float* xp = x + (((size_t)n * C + cq * 64) * H + h) * W + w;
#pragma unroll
    for (int i = 0; i < 16; ++i) {     // 4 channels per iter -> one u32 store
        uint32_t u = 0;
#pragma unroll
        for (int b = 0; b < 4; ++b) {
            float v = (w < 56) ? xp[(size_t)(i * 4 + b) * (H * W)] : 0.0f;
            uint32_t t = (v < 0.0f) ? 0xFFu : ((v != 0.0f) ? 1u : 0u);
            u |= t << (8 * b);
        }
        if (w < 56)
            *(uint32_t*)(st + w * OST + cq * 64 + i * 4) = u;
    }
    __syncthreads();
    // coalesced out: 56 pixels x 256 B contiguous at (h+1, 1)
    int8_t* dst = Aq + (((size_t)n * HP + h + 1) * HP + 1) * C;
    for (int idx = threadIdx.x; idx < 56 * 16; idx += 256) {
        int pix = idx >> 4, c16 = idx & 15;
        *(v4i*)(dst + (size_t)pix * C + c16 * 16) =
            *(const v4i*)(st + pix * OST + c16 * 16);
    }
}

// ---------------- pack weights into B-fragment order -----------------------
__global__ __launch_bounds__(64)
void pack_w_kernel(const float* __restrict__ wa, const float* __restrict__ wb,
                   int8_t* __restrict__ B1, int8_t* __restrict__ B2) {
    const int kstep = blockIdx.x;   // 0..35 (= tap*4 + cich)
    const int nfrag = blockIdx.y;   // 0..15
    const float* wsrc = blockIdx.z ? wb : wa;
    int8_t* dst       = blockIdx.z ? B2 : B1;
    const int lane = threadIdx.x, quad = lane >> 4, l16 = lane & 15;
    const int co = nfrag * 16 + l16;
    uint32_t pk[4];
#pragma unroll
    for (int d = 0; d < 4; ++d) {
        uint32_t u = 0;
#pragma unroll
        for (int bb = 0; bb < 4; ++bb) {
            int k = kstep * 64 + quad * 16 + d * 4 + bb;
            int tap = k >> 8, ci = k & 255;
            float v = wsrc[((size_t)co * C + ci) * 9 + tap];
            uint32_t t = (v < 0.0f) ? 0xFFu : ((v != 0.0f) ? 1u : 0u);
            u |= t << (8 * bb);
        }
        pk[d] = u;
    }
    uint4 st; st.x = pk[0]; st.y = pk[1]; st.z = pk[2]; st.w = pk[3];
    *(uint4*)(dst + ((size_t)(nfrag * 36 + kstep) * 64 + lane) * 16) = st;
}

// ---------------- zero halos of both padded activation buffers -------------
__global__ __launch_bounds__(256)
void halo_zero_kernel(int8_t* __restrict__ Aq, int8_t* __restrict__ Bq) {
    const int n = blockIdx.x;
    int8_t* buf = blockIdx.y ? Bq : Aq;
    const v4i z = (v4i){0, 0, 0, 0};
    for (int idx = threadIdx.x; idx < 228 * 16; idx += 256) {
        int px = idx >> 4, c16 = idx & 15;
        int row, col;
        if (px < 58)       { row = 0;  col = px; }
        else if (px < 116) { row = 57; col = px - 58; }
        else { int i = px - 116; row = 1 + (i >> 1); col = (i & 1) * 57; }
        *(v4i*)(buf + (((size_t)n * HP + row) * HP + col) * C + c16 * 16) = z;
    }
}

// ---------------- BN constants (match prior absmax-0 double path) ----------
__global__ __launch_bounds__(256)
void bn_prep_kernel(const float* g1, const float* b1, const float* m1, const float* v1,
                    const float* g2, const float* b2, const float* m2, const float* v2,
                    float* __restrict__ sc, float* __restrict__ sh) {
    const int co = threadIdx.x;
    const float* g = blockIdx.x ? g2 : g1;
    const float* b = blockIdx.x ? b2 : b1;
    const float* m = blockIdx.x ? m2 : m1;
    const float* v = blockIdx.x ? v2 : v1;
    double scd = (double)g[co] / sqrt((double)v[co] + 1e-5);
    sc[blockIdx.x * C + co] = (float)scd;
    sh[blockIdx.x * C + co] = (float)((double)b[co] - (double)m[co] * scd);
}

// ---------------- K-loop (templated on per-wave m-frag count) --------------
template <int MF>
__device__ __forceinline__ void kloop(const int8_t* __restrict__ lds8,
                                      const int (&abase)[4],
                                      const int8_t* __restrict__ b0,
                                      const int8_t* __restrict__ b1,
                                      const int8_t* __restrict__ b2,
                                      const int8_t* __restrict__ b3,
                                      v4i (&acc)[4][4]) {
#pragma unroll 1
    for (int t = 0; t < 9; ++t) {
        const int r = (t >= 6) ? 2 : ((t >= 3) ? 1 : 0);
        const int c = t - 3 * r;
        const int au = r * SLOT + c * PPIX;
#pragma unroll
        for (int ci = 0; ci < 4; ++ci) {
            v4i bf[4];
            bf[0] = *(const v4i*)(b0 + ci * 1024);
            bf[1] = *(const v4i*)(b1 + ci * 1024);
            bf[2] = *(const v4i*)(b2 + ci * 1024);
            bf[3] = *(const v4i*)(b3 + ci * 1024);
            v4i afr[MF];
#pragma unroll
            for (int f = 0; f < MF; ++f)
                afr[f] = *(const v4i*)(lds8 + abase[f] + au + ci * 64);
            __builtin_amdgcn_s_setprio(1);
#pragma unroll
            for (int f = 0; f < MF; ++f)
#pragma unroll
                for (int nf = 0; nf < 4; ++nf)
                    acc[f][nf] = __builtin_amdgcn_mfma_i32_16x16x64_i8(
                        afr[f], bf[nf], acc[f][nf], 0, 0, 0);
            __builtin_amdgcn_s_setprio(0);
        }
        b0 += 4096; b1 += 4096; b2 += 4096; b3 += 4096;
    }
}

// ---------------- the conv kernels -----------------------------------------
// STAGE 1: GEMM -> BN -> ternarize -> LDS transpose -> coalesced NHWC i8.
// STAGE 2: GEMM -> BN -> LDS transpose -> +residual -> clip -> coalesced
//          fp32 NCHW (w-contiguous float4 runs).
// 512 threads = 8 waves as 2Mx4N: wave (wrow, wcol); wrow0 m-frags 0..3,
// wrow1 m-frags 4..6; nfrags wcol*4..wcol*4+3.
template <int STAGE>
__global__ __launch_bounds__(512, 4)
void mconv_kernel(const int8_t* __restrict__ Aq, const int8_t* __restrict__ Bpk,
                  const float* __restrict__ scp, const float* __restrict__ shp,
                  const float* __restrict__ resid,
                  int8_t* __restrict__ Bout, float* __restrict__ out) {
    const int h2 = blockIdx.x;   // output rows h2*2, h2*2+1
    const int n  = blockIdx.y;
    const int tid = threadIdx.x;
    const int wv = tid >> 6, lane = tid & 63, quad = lane >> 4, l16 = lane & 15;
    const int wrow = wv >> 2, wcol = wv & 3;

    __shared__ int8_t lds[4 * SLOT];   // 63104 B -> 2 blocks/CU

    // stage input rows h2*2 .. h2*2+3 (row d -> d*SLOT, pixel stride PPIX)
    const int8_t* gA = Aq + ((size_t)n * HP + h2 * 2) * HP * C;
    for (int idx = tid; idx < 4 * HP * 16; idx += 512) {
        int pix = idx >> 4, c16 = idx & 15;        // pix = d*HP + col
        *(v4i*)(lds + pix * PPIX + c16 * 16) =
            *(const v4i*)(gA + (size_t)pix * C + c16 * 16);
    }
    __syncthreads();

    // per-lane A bases for this wave's m-frags: fg = wrow*4 + f
    int abase[4];
#pragma unroll
    for (int f = 0; f < 4; ++f) {
        int fg = wrow * 4 + f;
        if (fg > 6) fg = 6;                 // wrow1 f=3 unused (clamp)
        int mm = fg * 16 + l16;
        int hl = (mm >= 56) ? 1 : 0;
        abase[f] = hl * SLOT + (mm - 56 * hl) * PPIX + quad * 16;
    }

    // B fragment pointers: nfrags wcol*4 .. wcol*4+3
    const int8_t* b0 = Bpk + (size_t)((wcol * 4 + 0) * 36) * 1024 + lane * 16;
    const int8_t* b1 = Bpk + (size_t)((wcol * 4 + 1) * 36) * 1024 + lane * 16;
    const int8_t* b2 = Bpk + (size_t)((wcol * 4 + 2) * 36) * 1024 + lane * 16;
    const int8_t* b3 = Bpk + (size_t)((wcol * 4 + 3) * 36) * 1024 + lane * 16;

    v4i acc[4][4];
#pragma unroll
    for (int f = 0; f < 4; ++f)
#pragma unroll
        for (int nf = 0; nf < 4; ++nf) acc[f][nf] = (v4i){0, 0, 0, 0};

    if (wrow == 0) kloop<4>(lds, abase, b0, b1, b2, b3, acc);
    else           kloop<3>(lds, abase, b0, b1, b2, b3, acc);

    // ---- epilogue ----
    if (STAGE == 1) {
        __syncthreads();   // K-loop LDS dead; reuse as transpose buffer
#pragma unroll
        for (int nf = 0; nf < 4; ++nf) {
            const int co = (wcol * 4 + nf) * 16 + l16;
            const float scale = scp[co], shift = shp[co];
#pragma unroll
            for (int f = 0; f < 4; ++f) {
                if (f < 3 || wrow == 0) {          // wave-uniform guard
                    const int mmb = (wrow * 4 + f) * 16 + quad * 4;
#pragma unroll
                    for (int reg = 0; reg < 4; ++reg) {
                        float v = __fadd_rn(__fmul_rn((float)acc[f][nf][reg], scale), shift);
                        int8_t t8 = (v < 0.0f) ? (int8_t)-1
                                  : ((v != 0.0f) ? (int8_t)1 : (int8_t)0);
                        lds[(mmb + reg) * OST + co] = t8;
                    }
                }
            }
        }
        __syncthreads();
        // coalesced out: 112 pixels x 256 B
        for (int idx = tid; idx < 112 * 16; idx += 512) {
            int mm = idx >> 4, c16 = idx & 15;
            int hl = (mm >= 56) ? 1 : 0;
            int ww = mm - 56 * hl;
            int oh = h2 * 2 + hl;
            *(v4i*)(Bout + (((size_t)n * HP + oh + 1) * HP + ww + 1) * C + c16 * 16)
                = *(const v4i*)(lds + mm * OST + c16 * 16);
        }
    } else {
        // -------- stage-2: transpose through LDS, then coalesced NCHW ------
        float* fld = (float*)lds;   // [cop(128)][FST=116 dw]: 59,392 B
#pragma unroll 1
        for (int half = 0; half < 2; ++half) {
            __syncthreads();        // K-loop A-data (or prev half) dead
            if ((wcol >> 1) == half) {   // waves with co in [half*128, +128)
                const int copb = (wcol & 1) * 64;
#pragma unroll
                for (int nf = 0; nf < 4; ++nf) {
                    const int cop = copb + nf * 16 + l16;
                    const int co  = half * 128 + cop;
                    const float scale = scp[co], shift = shp[co];
#pragma unroll
                    for (int f = 0; f < 4; ++f) {
                        if (f < 3 || wrow == 0) {  // wave-uniform guard
                            float4 vv;
                            vv.x = __fadd_rn(__fmul_rn((float)acc[f][nf][0], scale), shift);
                            vv.y = __fadd_rn(__fmul_rn((float)acc[f][nf][1], scale), shift);
                            vv.z = __fadd_rn(__fmul_rn((float)acc[f][nf][2], scale), shift);
                            vv.w = __fadd_rn(__fmul_rn((float)acc[f][nf][3], scale), shift);
                            *(float4*)(fld + cop * FST + (wrow * 4 + f) * 16 + quad * 4) = vv;
                        }
                    }
                }
            }
            __syncthreads();
            // 128 co x 28 float4-chunks (2 rows x 14) = 3584 = 512 x 7
            for (int idx = tid; idx < 128 * 28; idx += 512) {
                int cop = idx / 28, j = idx - cop * 28;
                int row = (j >= 14) ? 1 : 0;
                int w4  = (j - row * 14) * 4;
                int mm  = row * 56 + w4;
                int co  = half * 128 + cop;
                float4 v = *(const float4*)(fld + cop * FST + mm);
                size_t gidx = (((size_t)n * C + co) * H + h2 * 2 + row) * W + w4;
                float4 rv = *(const float4*)(resid + gidx);
                float4 ov;
                ov.x = fminf(1.0f, fmaxf(-1.0f, v.x + rv.x));
                ov.y = fminf(1.0f, fmaxf(-1.0f, v.y + rv.y));
                ov.z = fminf(1.0f, fmaxf(-1.0f, v.z + rv.z));
                ov.w = fminf(1.0f, fmaxf(-1.0f, v.w + rv.w));
                *(float4*)(out + gidx) = ov;
            }
        }
    }
}

extern "C" void kernel_launch(void* const* d_in, const int* in_sizes, int n_in,
                              void* d_out, int out_size, void* d_ws, size_t ws_size,
                              hipStream_t stream) {
    const float* x  = (const float*)d_in[0];
    const float* w1 = (const float*)d_in[1];
    const float* g1 = (const float*)d_in[2];
    const float* b1 = (const float*)d_in[3];
    const float* m1 = (const float*)d_in[4];
    const float* v1 = (const float*)d_in[5];
    const float* w2 = (const float*)d_in[6];
    const float* g2 = (const float*)d_in[7];
    const float* b2 = (const float*)d_in[8];
    const float* m2 = (const float*)d_in[9];
    const float* v2 = (const float*)d_in[10];
    float* out = (float*)d_out;

    uint8_t* ws = (uint8_t*)d_ws;
    const size_t ASZ = (size_t)NB * HP * HP * C;       // 55,083,008 B per act buffer
    const size_t WPK = (size_t)16 * 36 * 64 * 16;      // 589,824 B per packed weight
    int8_t* Aq   = (int8_t*)(ws);
    int8_t* Bq   = (int8_t*)(ws + ASZ);
    int8_t* Bpk1 = (int8_t*)(ws + 2 * ASZ);
    int8_t* Bpk2 = (int8_t*)(ws + 2 * ASZ + WPK);
    float*  scb  = (float*)(ws + 2 * ASZ + 2 * WPK);           // [2][256]
    float*  shb  = (float*)(ws + 2 * ASZ + 2 * WPK + 2048);    // [2][256]

    halo_zero_kernel<<<dim3(NB, 2), 256, 0, stream>>>(Aq, Bq);
    bn_prep_kernel<<<dim3(2), 256, 0, stream>>>(g1, b1, m1, v1, g2, b2, m2, v2,
                                                scb, shb);
    pack_w_kernel<<<dim3(36, 16, 2), 64, 0, stream>>>(w1, w2, Bpk1, Bpk2);
    pack_x_kernel<<<dim3(H, NB), 256, 0, stream>>>(x, Aq);
    mconv_kernel<1><<<dim3(28, NB), 512, 0, stream>>>(Aq, Bpk1, scb, shb,
                                                      nullptr, Bq, nullptr);
    mconv_kernel<2><<<dim3(28, NB), 512, 0, stream>>>(Bq, Bpk2, scb + C, shb + C,
                                                      x, nullptr, out);
}

// Round 9
// 590.386 us; speedup vs baseline: 1.1943x; 1.0817x over previous
//
#include <hip/hip_runtime.h>
#include <stdint.h>

// ---------------------------------------------------------------------------
// Ternary 3x3 conv block via i8 MFMA implicit GEMM.
//
// Activations: NHWC i8 ternary {-1,0,+1}, padded [64][58][58][256], halo = 0.
// Weights pre-packed in MFMA B-fragment order:
//   Bpk[nfrag(16)][unit(36)][lane(64)][16B], unit = tap*4 + cich (k-chunk).
// mconv (round-5 config, best known 596us): M=112 (2 out rows) x N=256 x
//   K=2304, 8 waves N-split 32 each (acc[7][2] = 56 AGPRs + 64 arch = 120
//   regs <= 128 -> 2 blocks/CU), B-dbuf (1 unit ahead), 4 input rows in LDS
//   (63.1 KB). History: r4 1-row/3-blk reshape regressed (occupancy not
//   binding); r6 2-tile overlap spilled acc (+103MB scratch); r7 2Mx4N
//   halved LDS conflicts but dropping B-dbuf exposed L2 latency (156->182).
//   Register wall (128) + LDS (63KB) pin this shape; phases serialize.
// Round-8 change: merge pack_x + halo_zero + bn_prep + pack_w into ONE
//   prep_kernel (union grid, wave-uniform role branch) -> 6 launches -> 3.
//   Cross-round accounting shows a stable ~280us non-mconv component;
//   launch gaps + serialized small kernels are the attackable part.
//   C/D: col=lane&15, row=(lane>>4)*4+reg.
// ---------------------------------------------------------------------------

#define NB 64
#define C  256
#define H  56
#define W  56
#define HP 58
#define PPIX 272                 // padded bytes per pixel in LDS (17*16)
#define SLOT (HP * PPIX)         // bytes per LDS row slot
#define OST 272                  // stage-1 transpose row stride (256+16)
#define FST 116                  // stage-2 transpose stride in dwords (112+4)

// prep_kernel role partition
#define PX_N   (H * NB)          // 3584 pack_x blocks
#define HZ_N   (NB * 2)          // 128 halo blocks
#define BN_N   1                 // 1 bn_prep block
#define PW_N   288               // 1152 (kstep,nfrag,z) tuples / 4 per block
#define PREP_N (PX_N + HZ_N + BN_N + PW_N)   // 4001

typedef int v4i __attribute__((ext_vector_type(4)));

// ---------------- merged prep: pack_x | halo_zero | bn_prep | pack_w -------
__global__ __launch_bounds__(256)
void prep_kernel(const float* __restrict__ x, int8_t* __restrict__ Aq,
                 int8_t* __restrict__ Bq,
                 const float* __restrict__ g1, const float* __restrict__ b1,
                 const float* __restrict__ m1, const float* __restrict__ v1,
                 const float* __restrict__ g2, const float* __restrict__ b2,
                 const float* __restrict__ m2, const float* __restrict__ v2,
                 float* __restrict__ sc, float* __restrict__ sh,
                 const float* __restrict__ wa, const float* __restrict__ wb,
                 int8_t* __restrict__ B1, int8_t* __restrict__ B2) {
    const int bx = blockIdx.x;
    __shared__ int8_t st[56 * OST];    // pack_x staging (15.2 KB)

    if (bx < PX_N) {
        // ---------------- pack_x: NCHW fp32 -> padded NHWC ternary i8 ------
        const int h = bx % H, n = bx / H;
        const int w  = threadIdx.x & 63;   // 0..55 valid
        const int cq = threadIdx.x >> 6;   // 64-channel group

        const float* xp = x + (((size_t)n * C + cq * 64) * H + h) * W + w;
#pragma unroll
        for (int i = 0; i < 16; ++i) {     // 4 channels -> one u32 store
            uint32_t u = 0;
#pragma unroll
            for (int b = 0; b < 4; ++b) {
                float v = (w < 56) ? xp[(size_t)(i * 4 + b) * (H * W)] : 0.0f;
                uint32_t t = (v < 0.0f) ? 0xFFu : ((v != 0.0f) ? 1u : 0u);
                u |= t << (8 * b);
            }
            if (w < 56)
                *(uint32_t*)(st + w * OST + cq * 64 + i * 4) = u;
        }
        __syncthreads();
        // coalesced out: 56 pixels x 256 B contiguous at (h+1, 1)
        int8_t* dst = Aq + (((size_t)n * HP + h + 1) * HP + 1) * C;
        for (int idx = threadIdx.x; idx < 56 * 16; idx += 256) {
            int pix = idx >> 4, c16 = idx & 15;
            *(v4i*)(dst + (size_t)pix * C + c16 * 16) =
                *(const v4i*)(st + pix * OST + c16 * 16);
        }
    } else if (bx < PX_N + HZ_N) {
        // ---------------- halo_zero: borders of both padded act buffers ----
        const int i = bx - PX_N;
        const int n = i >> 1;
        int8_t* buf = (i & 1) ? Bq : Aq;
        const v4i z = (v4i){0, 0, 0, 0};
        for (int idx = threadIdx.x; idx < 228 * 16; idx += 256) {
            int px = idx >> 4, c16 = idx & 15;
            int row, col;
            if (px < 58)       { row = 0;  col = px; }
            else if (px < 116) { row = 57; col = px - 58; }
            else { int k = px - 116; row = 1 + (k >> 1); col = (k & 1) * 57; }
            *(v4i*)(buf + (((size_t)n * HP + row) * HP + col) * C + c16 * 16) = z;
        }
    } else if (bx < PX_N + HZ_N + BN_N) {
        // ---------------- bn_prep (both param sets) ------------------------
        const int co = threadIdx.x;
#pragma unroll
        for (int s = 0; s < 2; ++s) {
            const float* g = s ? g2 : g1;
            const float* b = s ? b2 : b1;
            const float* m = s ? m2 : m1;
            const float* v = s ? v2 : v1;
            double scd = (double)g[co] / sqrt((double)v[co] + 1e-5);
            sc[s * C + co] = (float)scd;
            sh[s * C + co] = (float)((double)b[co] - (double)m[co] * scd);
        }
    } else {
        // ---------------- pack_w: weights -> B-fragment order --------------
        const int jb = bx - (PX_N + HZ_N + BN_N);      // 0..287
        const int j  = jb * 4 + (threadIdx.x >> 6);    // 0..1151
        const int kstep = j % 36;
        const int nfrag = (j / 36) % 16;
        const int z     = j / 576;
        const float* wsrc = z ? wb : wa;
        int8_t* dst       = z ? B2 : B1;
        const int lane = threadIdx.x & 63, quad = (lane >> 4), l16 = lane & 15;
        const int co = nfrag * 16 + l16;
        uint32_t pk[4];
#pragma unroll
        for (int d = 0; d < 4; ++d) {
            uint32_t u = 0;
#pragma unroll
            for (int bb = 0; bb < 4; ++bb) {
                int k = kstep * 64 + quad * 16 + d * 4 + bb;
                int tap = k >> 8, ci = k & 255;
                float v = wsrc[((size_t)co * C + ci) * 9 + tap];
                uint32_t t = (v < 0.0f) ? 0xFFu : ((v != 0.0f) ? 1u : 0u);
                u |= t << (8 * bb);
            }
            pk[d] = u;
        }
        uint4 s4; s4.x = pk[0]; s4.y = pk[1]; s4.z = pk[2]; s4.w = pk[3];
        *(uint4*)(dst + ((size_t)(nfrag * 36 + kstep) * 64 + lane) * 16) = s4;
    }
}

// ---------------- the conv kernels (round-5 config) ------------------------
// STAGE 1: GEMM -> BN -> ternarize -> LDS transpose -> coalesced NHWC i8.
// STAGE 2: GEMM -> BN -> LDS transpose -> +residual -> clip -> coalesced
//          fp32 NCHW (w-contiguous float4 runs).
// 512 threads = 8 waves; wave wv owns nfrags {wv*2, wv*2+1} (N-cols wv*32..+31).
template <int STAGE>
__global__ __launch_bounds__(512, 4)
void mconv_kernel(const int8_t* __restrict__ Aq, const int8_t* __restrict__ Bpk,
                  const float* __restrict__ scp, const float* __restrict__ shp,
                  const float* __restrict__ resid,
                  int8_t* __restrict__ Bout, float* __restrict__ out) {
    const int h2 = blockIdx.x;   // output rows h2*2, h2*2+1
    const int n  = blockIdx.y;
    const int tid = threadIdx.x;
    const int wv = tid >> 6, lane = tid & 63, quad = lane >> 4, l16 = lane & 15;

    __shared__ int8_t lds[4 * SLOT];   // 63104 B

    // stage input rows h2*2 .. h2*2+3 (row d -> d*SLOT, pixel stride PPIX)
    const int8_t* gA = Aq + ((size_t)n * HP + h2 * 2) * HP * C;
    for (int idx = tid; idx < 4 * HP * 16; idx += 512) {
        int pix = idx >> 4, c16 = idx & 15;        // pix = d*HP + col
        *(v4i*)(lds + pix * PPIX + c16 * 16) =
            *(const v4i*)(gA + (size_t)pix * C + c16 * 16);
    }
    __syncthreads();

    // per-lane A bases: m = f*16 + l16 -> (hl, w)
    int abase[7];
#pragma unroll
    for (int f = 0; f < 7; ++f) {
        int mm = f * 16 + l16;
        int hl = (mm >= 56) ? 1 : 0;
        int w  = mm - 56 * hl;
        abase[f] = hl * SLOT + w * PPIX + quad * 16;
    }

    // B fragment pointers: wave wv owns nfrags wv*2, wv*2+1
    const int8_t* bq0 = Bpk + (size_t)((wv * 2 + 0) * 36) * 1024 + lane * 16;
    const int8_t* bq1 = Bpk + (size_t)((wv * 2 + 1) * 36) * 1024 + lane * 16;

    v4i bcur[2];
    bcur[0] = *(const v4i*)(bq0);
    bcur[1] = *(const v4i*)(bq1);

    v4i acc[7][2];
#pragma unroll
    for (int f = 0; f < 7; ++f)
#pragma unroll
        for (int nf = 0; nf < 2; ++nf) acc[f][nf] = (v4i){0, 0, 0, 0};

#pragma unroll 1
    for (int t = 0; t < 9; ++t) {
        const int r = (t >= 6) ? 2 : ((t >= 3) ? 1 : 0);
        const int c = t - 3 * r;
        const int au = r * SLOT + c * PPIX;
#pragma unroll
        for (int ci = 0; ci < 4; ++ci) {
            // prefetch next unit's B fragments (flat-contiguous; final
            // iteration reads 1KB past this nfrag's tail -> still inside d_ws)
            v4i bn0 = *(const v4i*)(bq0 + (ci + 1) * 1024);
            v4i bn1 = *(const v4i*)(bq1 + (ci + 1) * 1024);
            v4i afr[7];
#pragma unroll
            for (int f = 0; f < 7; ++f)
                afr[f] = *(const v4i*)(lds + abase[f] + au + ci * 64);
            __builtin_amdgcn_s_setprio(1);
#pragma unroll
            for (int f = 0; f < 7; ++f) {
                acc[f][0] = __builtin_amdgcn_mfma_i32_16x16x64_i8(
                    afr[f], bcur[0], acc[f][0], 0, 0, 0);
                acc[f][1] = __builtin_amdgcn_mfma_i32_16x16x64_i8(
                    afr[f], bcur[1], acc[f][1], 0, 0, 0);
            }
            __builtin_amdgcn_s_setprio(0);
            bcur[0] = bn0;
            bcur[1] = bn1;
        }
        bq0 += 4096;
        bq1 += 4096;
    }

    // ---- epilogue ----
    if (STAGE == 1) {
        __syncthreads();   // K-loop LDS dead; reuse as transpose buffer
#pragma unroll
        for (int nf = 0; nf < 2; ++nf) {
            const int co = (wv * 2 + nf) * 16 + l16;
            const float scale = scp[co], shift = shp[co];
#pragma unroll
            for (int f = 0; f < 7; ++f) {
#pragma unroll
                for (int reg = 0; reg < 4; ++reg) {
                    int mm = f * 16 + quad * 4 + reg;
                    float v = __fadd_rn(__fmul_rn((float)acc[f][nf][reg], scale), shift);
                    int8_t t8 = (v < 0.0f) ? (int8_t)-1
                              : ((v != 0.0f) ? (int8_t)1 : (int8_t)0);
                    lds[mm * OST + co] = t8;
                }
            }
        }
        __syncthreads();
        // coalesced out: 112 pixels x 256 B
        for (int idx = tid; idx < 112 * 16; idx += 512) {
            int mm = idx >> 4, c16 = idx & 15;
            int hl = (mm >= 56) ? 1 : 0;
            int ww = mm - 56 * hl;
            int oh = h2 * 2 + hl;
            *(v4i*)(Bout + (((size_t)n * HP + oh + 1) * HP + ww + 1) * C + c16 * 16)
                = *(const v4i*)(lds + mm * OST + c16 * 16);
        }
    } else {
        // -------- stage-2: transpose through LDS, then coalesced NCHW ------
        float* fld = (float*)lds;   // [cop(128)][FST=116 dw]: 59,392 B
#pragma unroll 1
        for (int half = 0; half < 2; ++half) {
            __syncthreads();        // K-loop A-data (or prev half) dead
            if ((wv >> 2) == half) {
#pragma unroll
                for (int nf = 0; nf < 2; ++nf) {
                    const int co = (wv * 2 + nf) * 16 + l16;
                    const int cop = co - half * 128;
                    const float scale = scp[co], shift = shp[co];
#pragma unroll
                    for (int f = 0; f < 7; ++f) {
                        float4 vv;
                        vv.x = __fadd_rn(__fmul_rn((float)acc[f][nf][0], scale), shift);
                        vv.y = __fadd_rn(__fmul_rn((float)acc[f][nf][1], scale), shift);
                        vv.z = __fadd_rn(__fmul_rn((float)acc[f][nf][2], scale), shift);
                        vv.w = __fadd_rn(__fmul_rn((float)acc[f][nf][3], scale), shift);
                        // mm = f*16 + quad*4 (+reg): 4-aligned -> one float4
                        *(float4*)(fld + cop * FST + f * 16 + quad * 4) = vv;
                    }
                }
            }
            __syncthreads();
            // 128 co x 28 float4-chunks (2 rows x 14) = 3584 = 512 x 7
            for (int idx = tid; idx < 128 * 28; idx += 512) {
                int cop = idx / 28, j = idx - cop * 28;
                int row = (j >= 14) ? 1 : 0;
                int w4  = (j - row * 14) * 4;
                int mm  = row * 56 + w4;
                int co  = half * 128 + cop;
                float4 v = *(const float4*)(fld + cop * FST + mm);
                size_t gidx = (((size_t)n * C + co) * H + h2 * 2 + row) * W + w4;
                float4 rv = *(const float4*)(resid + gidx);
                float4 ov;
                ov.x = fminf(1.0f, fmaxf(-1.0f, v.x + rv.x));
                ov.y = fminf(1.0f, fmaxf(-1.0f, v.y + rv.y));
                ov.z = fminf(1.0f, fmaxf(-1.0f, v.z + rv.z));
                ov.w = fminf(1.0f, fmaxf(-1.0f, v.w + rv.w));
                *(float4*)(out + gidx) = ov;
            }
        }
    }
}

extern "C" void kernel_launch(void* const* d_in, const int* in_sizes, int n_in,
                              void* d_out, int out_size, void* d_ws, size_t ws_size,
                              hipStream_t stream) {
    const float* x  = (const float*)d_in[0];
    const float* w1 = (const float*)d_in[1];
    const float* g1 = (const float*)d_in[2];
    const float* b1 = (const float*)d_in[3];
    const float* m1 = (const float*)d_in[4];
    const float* v1 = (const float*)d_in[5];
    const float* w2 = (const float*)d_in[6];
    const float* g2 = (const float*)d_in[7];
    const float* b2 = (const float*)d_in[8];
    const float* m2 = (const float*)d_in[9];
    const float* v2 = (const float*)d_in[10];
    float* out = (float*)d_out;

    uint8_t* ws = (uint8_t*)d_ws;
    const size_t ASZ = (size_t)NB * HP * HP * C;       // 55,083,008 B per act buffer
    const size_t WPK = (size_t)16 * 36 * 64 * 16;      // 589,824 B per packed weight
    int8_t* Aq   = (int8_t*)(ws);
    int8_t* Bq   = (int8_t*)(ws + ASZ);
    int8_t* Bpk1 = (int8_t*)(ws + 2 * ASZ);
    int8_t* Bpk2 = (int8_t*)(ws + 2 * ASZ + WPK);
    float*  scb  = (float*)(ws + 2 * ASZ + 2 * WPK);           // [2][256]
    float*  shb  = (float*)(ws + 2 * ASZ + 2 * WPK + 2048);    // [2][256]

    prep_kernel<<<dim3(PREP_N), 256, 0, stream>>>(
        x, Aq, Bq, g1, b1, m1, v1, g2, b2, m2, v2, scb, shb, w1, w2, Bpk1, Bpk2);
    mconv_kernel<1><<<dim3(28, NB), 512, 0, stream>>>(Aq, Bpk1, scb, shb,
                                                      nullptr, Bq, nullptr);
    mconv_kernel<2><<<dim3(28, NB), 512, 0, stream>>>(Bq, Bpk2, scb + C, shb + C,
                                                      x, nullptr, out);
}